// Round 3
// baseline (458.410 us; speedup 1.0000x reference)
//
#include <hip/hip_runtime.h>
#include <hip/hip_bf16.h>

#define N_TOK 8192
#define DM 768
#define DFF 2048
#define NE 8
#define SHARED_BASE 17408   // routed padded slots max 16384 + 8*127 -> 17408
#define TOTAL_ROWS 25600

typedef __attribute__((ext_vector_type(8))) __bf16 bf16x8;
typedef __attribute__((ext_vector_type(4))) float f32x4;

__device__ __forceinline__ unsigned short f2bf(float f) {
  union { float f; unsigned u; } a; a.f = f;
  unsigned r = a.u + 0x7FFFu + ((a.u >> 16) & 1u);
  return (unsigned short)(r >> 16);
}

__device__ __forceinline__ void gload16(const void* g, void* l) {
  __builtin_amdgcn_global_load_lds((const __attribute__((address_space(1))) void*)g,
                                   (__attribute__((address_space(3))) void*)l, 16, 0, 0);
}

// ---------------- prep kernels ----------------

__global__ void cvt_x_kernel(const float4* __restrict__ src, ushort4* __restrict__ dst, int n4) {
  int stride = gridDim.x * blockDim.x;
  for (int i = blockIdx.x * blockDim.x + threadIdx.x; i < n4; i += stride) {
    float4 v = src[i];
    ushort4 o;
    o.x = f2bf(v.x); o.y = f2bf(v.y); o.z = f2bf(v.z); o.w = f2bf(v.w);
    dst[i] = o;
  }
}

__global__ void transpose_cvt_kernel(const float* __restrict__ src, unsigned short* __restrict__ dst,
                                     int R, int C) {
  __shared__ float tile[64][65];
  const float* s = src + (size_t)blockIdx.z * R * C;
  unsigned short* d = dst + (size_t)blockIdx.z * R * C;
  int c0 = blockIdx.x * 64, r0 = blockIdx.y * 64;
  int tx = threadIdx.x & 63, ty = threadIdx.x >> 6;
#pragma unroll
  for (int i = 0; i < 16; i++) {
    int row = i * 4 + ty;
    tile[row][tx] = s[(size_t)(r0 + row) * C + c0 + tx];
  }
  __syncthreads();
#pragma unroll
  for (int i = 0; i < 16; i++) {
    int row = i * 4 + ty;
    d[(size_t)(c0 + row) * R + r0 + tx] = f2bf(tile[tx][row]);
  }
}

// gate: 4 waves x 4 tokens each, gw transposed in LDS, fp64 accumulation, no atomics.
__global__ __launch_bounds__(256) void gate_kernel(
    const float* __restrict__ x, const float* __restrict__ gw,
    float* __restrict__ probs, int* __restrict__ idxo) {
  __shared__ float gws[8][768];
  const int tid = threadIdx.x;
  for (int i = tid; i < DM * 2; i += 256) {
    float4 v = ((const float4*)gw)[i];
    int dd = i >> 1;
    int e0 = (i & 1) * 4;
    gws[e0 + 0][dd] = v.x; gws[e0 + 1][dd] = v.y;
    gws[e0 + 2][dd] = v.z; gws[e0 + 3][dd] = v.w;
  }
  __syncthreads();
  const int lane = tid & 63, wv = tid >> 6;
  const int tok0 = blockIdx.x * 16 + wv * 4;
  for (int i = 0; i < 4; i++) {
    const int n = tok0 + i;
    const float* xr = x + (size_t)n * DM;
    float xv[12];
#pragma unroll
    for (int it = 0; it < 12; it++) xv[it] = xr[it * 64 + lane];
    double acc[8];
#pragma unroll
    for (int e = 0; e < 8; e++) {
      double a = 0.0;
#pragma unroll
      for (int it = 0; it < 12; it++) a += (double)xv[it] * (double)gws[e][it * 64 + lane];
      acc[e] = a;
    }
#pragma unroll
    for (int off = 32; off > 0; off >>= 1)
#pragma unroll
      for (int e = 0; e < 8; e++) acc[e] += __shfl_xor(acc[e], off);
    if (lane == 0) {
      int e0 = 0; double v0 = acc[0];
#pragma unroll
      for (int e = 1; e < 8; e++) if (acc[e] > v0) { v0 = acc[e]; e0 = e; }
      int e1 = -1; double v1 = -1e300;
#pragma unroll
      for (int e = 0; e < 8; e++) if (e != e0 && acc[e] > v1) { v1 = acc[e]; e1 = e; }
      double p0 = 1.0 / (1.0 + exp(v1 - v0));
      probs[n * 2 + 0] = (float)p0;
      probs[n * 2 + 1] = (float)(1.0 - p0);
      idxo[n * 2 + 0] = e0;
      idxo[n * 2 + 1] = e1;
    }
  }
}

// route: single block, deterministic prefix-scan scatter (128-aligned segments).
__global__ __launch_bounds__(256) void route_kernel(
    const int* __restrict__ idxo, const float* __restrict__ probs,
    int* __restrict__ cnt, int* __restrict__ offs,
    int* __restrict__ list, float* __restrict__ pslot) {
  __shared__ int lcnt[256][8];
  __shared__ int lstart[256][8];
  __shared__ int base[8];
  const int t = threadIdx.x;
#pragma unroll
  for (int e = 0; e < 8; e++) lcnt[t][e] = 0;
  __syncthreads();
  const int i0 = t * 64;
  for (int j = 0; j < 64; j++) {
    int e = idxo[i0 + j];
    lcnt[t][e]++;
  }
  __syncthreads();
  if (t < 8) {
    int run = 0;
    for (int tt = 0; tt < 256; tt++) { lstart[tt][t] = run; run += lcnt[tt][t]; }
    base[t] = run;
  }
  __syncthreads();
  if (t == 0) {
    int cum = 0;
    for (int e = 0; e < 8; e++) {
      int tot = base[e];
      cnt[e] = tot; offs[e] = cum;
      base[e] = cum;
      cum += (tot + 127) & ~127;
    }
    offs[8] = cum;
  }
  __syncthreads();
#pragma unroll
  for (int e = 0; e < 8; e++) lcnt[t][e] = base[e] + lstart[t][e];
  for (int j = 0; j < 64; j++) {
    int i = i0 + j;
    int e = idxo[i];
    int pos = lcnt[t][e]++;
    list[pos] = i >> 1;
    pslot[pos] = probs[i];
  }
}

// ---------------- GEMM1: H = silu(x@w1) * (x@w3) ----------------
// 256(M tokens) x 128(F, both w1&w3 => N=256 B-rows), BK=64, 512 thr = 8 waves (4M x 2N).
// Wave tile 64M x 128N; each wave holds h1 (nj 0-3) and h3 (nj 4-7) for the SAME f-cols.
// 2-phase: stage(t+1 -> buf^1) issued before compute(buf); one drain barrier per K-step.
__global__ __launch_bounds__(512, 2) void gemm1_kernel(
    const char* __restrict__ xb,     // bf16 [8192][768]
    const char* __restrict__ w1T,    // bf16 [8][2048][768]
    const char* __restrict__ w3T,
    const char* __restrict__ sw1T,   // bf16 [2048][768]
    const char* __restrict__ sw3T,
    const int* __restrict__ list, const int* __restrict__ cnt, const int* __restrict__ offs,
    unsigned short* __restrict__ Hb) // bf16 [25600][2048]
{
  __shared__ __attribute__((aligned(128))) unsigned char lds[131072]; // 2 bufs x (A 32K + B 32K)

  const int by = blockIdx.y;
  const int f0 = blockIdx.x * 128;
  const int tid = threadIdx.x;
  const int lane = tid & 63;
  const int wv = tid >> 6;        // 0..7
  const int wm = wv >> 1;         // 0..3
  const int wn = wv & 1;          // 0..1
  const int ml = lane & 15, kg = lane >> 4;

  const char *w1p, *w3p;
  int base_slot, tbase, cnt_e, cnt_pad = 1 << 30, offs_e = 0;
  const bool is_shared = (by >= 256);
  if (!is_shared) {
    int e = by >> 5, t = by & 31;
    cnt_e = cnt[e];
    if (t * 256 >= cnt_e) return;
    cnt_pad = (cnt_e + 127) & ~127;
    offs_e = offs[e];
    base_slot = offs_e + t * 256;
    tbase = t * 256;
    w1p = w1T + (size_t)e * DFF * DM * 2;
    w3p = w3T + (size_t)e * DFF * DM * 2;
  } else {
    int t = by - 256;
    base_slot = SHARED_BASE + t * 256;
    tbase = t * 256;
    cnt_e = 1 << 30;
    w1p = sw1T; w3p = sw3T;
  }

  // staging sources (fixed across K-steps)
  const int srow = tid >> 3;      // 0..63
  const int schk = tid & 7;
  size_t abase[4];
#pragma unroll
  for (int it = 0; it < 4; it++) {
    int row = it * 64 + srow;     // 0..255
    int tok;
    if (is_shared) tok = tbase + row;
    else {
      int ie = tbase + row;
      if (ie >= cnt_e) ie = cnt_e - 1;
      tok = list[offs_e + ie];
    }
    abase[it] = (size_t)tok * (DM * 2) + (size_t)((schk ^ (row & 7)) << 4);
  }
  const char* bptr[4];
#pragma unroll
  for (int it = 0; it < 4; it++) {
    // B-row it*64+srow: it0=w1[f0+], it1=w3[f0+], it2=w1[f0+64+], it3=w3[f0+64+]
    const char* wp = (it & 1) ? w3p : w1p;
    int frow = f0 + ((it >> 1) << 6) + srow;
    bptr[it] = wp + (size_t)frow * (DM * 2) + (size_t)((schk ^ (srow & 7)) << 4);
  }

  f32x4 acc[4][8];
  const f32x4 z4 = {0.f, 0.f, 0.f, 0.f};
#pragma unroll
  for (int mi = 0; mi < 4; mi++)
#pragma unroll
    for (int nj = 0; nj < 8; nj++) acc[mi][nj] = z4;

#define G1_STAGE(ks, b) {                                                        \
    char* Ab_ = (char*)lds + (b) * 65536;                                        \
    char* Bb_ = Ab_ + 32768;                                                     \
    _Pragma("unroll")                                                            \
    for (int it = 0; it < 4; it++)                                               \
      gload16(xb + abase[it] + (ks) * 128, Ab_ + (it * 512 + tid) * 16);         \
    _Pragma("unroll")                                                            \
    for (int it = 0; it < 4; it++)                                               \
      gload16(bptr[it] + (ks) * 128, Bb_ + (it * 512 + tid) * 16);               \
  }

  G1_STAGE(0, 0);
  __syncthreads();
  int cur = 0;
  for (int ks = 0; ks < 12; ks++) {
    if (ks < 11) G1_STAGE(ks + 1, cur ^ 1);
    const char* Ab = (const char*)lds + cur * 65536;
    const char* Bb = Ab + 32768;
#pragma unroll
    for (int kk = 0; kk < 2; kk++) {
      const int kblk = kk * 4 + kg;
      const int chk = (kblk ^ (ml & 7)) << 4;
      bf16x8 af[4], bfr[8];
#pragma unroll
      for (int mi = 0; mi < 4; mi++)
        af[mi] = *(const bf16x8*)(Ab + (wm * 64 + mi * 16 + ml) * 128 + chk);
#pragma unroll
      for (int nj = 0; nj < 8; nj++)
        bfr[nj] = *(const bf16x8*)(Bb + (wn * 128 + nj * 16 + ml) * 128 + chk);
#pragma unroll
      for (int mi = 0; mi < 4; mi++)
#pragma unroll
        for (int nj = 0; nj < 8; nj++)
          acc[mi][nj] = __builtin_amdgcn_mfma_f32_16x16x32_bf16(af[mi], bfr[nj], acc[mi][nj], 0, 0, 0);
    }
    __syncthreads();
    cur ^= 1;
  }

#pragma unroll
  for (int mi = 0; mi < 4; mi++) {
#pragma unroll
    for (int r = 0; r < 4; r++) {
      int row = wm * 64 + mi * 16 + (lane >> 4) * 4 + r;
      if (!is_shared && tbase + row >= cnt_pad) continue;
      size_t hrow = (size_t)(base_slot + row) * DFF;
#pragma unroll
      for (int nj = 0; nj < 4; nj++) {
        float h1 = acc[mi][nj][r], h3 = acc[mi][nj + 4][r];
        float s = h1 / (1.0f + expf(-h1));
        Hb[hrow + f0 + wn * 64 + nj * 16 + ml] = f2bf(s * h3);
      }
    }
  }
#undef G1_STAGE
}

// ---------------- GEMM2: out += p * (H @ w2), all slots incl shared ----------------
// 256(M slots) x 128(D), BK=64 (32 steps), 512 thr = 8 waves (4M x 2N), wave 64x64.
__global__ __launch_bounds__(512, 2) void gemm2_kernel(
    const char* __restrict__ Hb,     // bf16 [25600][2048]
    const char* __restrict__ w2T,    // bf16 [8][768][2048]
    const char* __restrict__ sw2T,   // bf16 [768][2048]
    const int* __restrict__ list, const int* __restrict__ cnt, const int* __restrict__ offs,
    const float* __restrict__ pslot,
    float* __restrict__ out)
{
  __shared__ __attribute__((aligned(128))) unsigned char lds[98304]; // 2 bufs x (A 32K + B 16K)

  const int by = blockIdx.y;
  const int d0 = blockIdx.x * 128;
  const int tid = threadIdx.x;
  const int lane = tid & 63;
  const int wv = tid >> 6;
  const int wm = wv >> 1;         // 0..3
  const int wn = wv & 1;          // 0..1
  const int ml = lane & 15, kg = lane >> 4;

  const char* w2p;
  int base_slot, offs_e = 0, tbase, cnt_e;
  const bool is_shared = (by >= 256);
  if (!is_shared) {
    int e = by >> 5, t = by & 31;
    cnt_e = cnt[e];
    if (t * 256 >= cnt_e) return;
    offs_e = offs[e];
    base_slot = offs_e + t * 256;
    tbase = t * 256;
    w2p = w2T + (size_t)e * DM * DFF * 2;
  } else {
    int t = by - 256;
    base_slot = SHARED_BASE + t * 256;
    tbase = t * 256;
    cnt_e = 1 << 30;
    w2p = sw2T;
  }

  const int srow = tid >> 3, schk = tid & 7;
  size_t abase[4];
#pragma unroll
  for (int it = 0; it < 4; it++) {
    int row = it * 64 + srow;
    abase[it] = (size_t)(base_slot + row) * (DFF * 2) + (size_t)((schk ^ (row & 7)) << 4);
  }
  size_t bbase[2];
#pragma unroll
  for (int it = 0; it < 2; it++) {
    int row = it * 64 + srow;     // 0..127
    bbase[it] = (size_t)(d0 + row) * (DFF * 2) + (size_t)((schk ^ (row & 7)) << 4);
  }

  f32x4 acc[4][4];
  const f32x4 z4 = {0.f, 0.f, 0.f, 0.f};
#pragma unroll
  for (int mi = 0; mi < 4; mi++)
#pragma unroll
    for (int nj = 0; nj < 4; nj++) acc[mi][nj] = z4;

#define G2_STAGE(ks, b) {                                                        \
    char* Ab_ = (char*)lds + (b) * 49152;                                        \
    char* Bb_ = Ab_ + 32768;                                                     \
    _Pragma("unroll")                                                            \
    for (int it = 0; it < 4; it++)                                               \
      gload16(Hb + abase[it] + (ks) * 128, Ab_ + (it * 512 + tid) * 16);         \
    _Pragma("unroll")                                                            \
    for (int it = 0; it < 2; it++)                                               \
      gload16(w2p + bbase[it] + (ks) * 128, Bb_ + (it * 512 + tid) * 16);        \
  }

  G2_STAGE(0, 0);
  __syncthreads();
  int cur = 0;
  for (int ks = 0; ks < 32; ks++) {
    if (ks < 31) G2_STAGE(ks + 1, cur ^ 1);
    const char* Ab = (const char*)lds + cur * 49152;
    const char* Bb = Ab + 32768;
#pragma unroll
    for (int kk = 0; kk < 2; kk++) {
      const int kblk = kk * 4 + kg;
      const int chk = (kblk ^ (ml & 7)) << 4;
      bf16x8 af[4], bfr[4];
#pragma unroll
      for (int mi = 0; mi < 4; mi++)
        af[mi] = *(const bf16x8*)(Ab + (wm * 64 + mi * 16 + ml) * 128 + chk);
#pragma unroll
      for (int nj = 0; nj < 4; nj++)
        bfr[nj] = *(const bf16x8*)(Bb + (wn * 64 + nj * 16 + ml) * 128 + chk);
#pragma unroll
      for (int mi = 0; mi < 4; mi++)
#pragma unroll
        for (int nj = 0; nj < 4; nj++)
          acc[mi][nj] = __builtin_amdgcn_mfma_f32_16x16x32_bf16(af[mi], bfr[nj], acc[mi][nj], 0, 0, 0);
    }
    __syncthreads();
    cur ^= 1;
  }

#pragma unroll
  for (int mi = 0; mi < 4; mi++) {
#pragma unroll
    for (int r = 0; r < 4; r++) {
      int row = wm * 64 + mi * 16 + (lane >> 4) * 4 + r;
      int ie = tbase + row;
      if (!is_shared && ie >= cnt_e) continue;
      int tok; float p;
      if (is_shared) { tok = tbase + row; p = 1.0f; }
      else { int slot = offs_e + ie; tok = list[slot]; p = pslot[slot]; }
      float* orow = out + (size_t)tok * DM + d0;
#pragma unroll
      for (int nj = 0; nj < 4; nj++)
        atomicAdd(&orow[wn * 64 + nj * 16 + ml], p * acc[mi][nj][r]);
    }
  }
#undef G2_STAGE
}

// ---------------- launch ----------------

extern "C" void kernel_launch(void* const* d_in, const int* in_sizes, int n_in,
                              void* d_out, int out_size, void* d_ws, size_t ws_size,
                              hipStream_t stream) {
  const float* x   = (const float*)d_in[0];
  const float* gw  = (const float*)d_in[1];
  const float* w1  = (const float*)d_in[2];
  const float* w3  = (const float*)d_in[3];
  const float* w2  = (const float*)d_in[4];
  const float* sw1 = (const float*)d_in[5];
  const float* sw3 = (const float*)d_in[6];
  const float* sw2 = (const float*)d_in[7];
  float* out = (float*)d_out;
  char* ws = (char*)d_ws;

  char* xb    = ws;                      // 12582912
  char* w1T   = xb    + 12582912;        // 25165824
  char* w3T   = w1T   + 25165824;
  char* w2T   = w3T   + 25165824;
  char* sw1T  = w2T   + 25165824;        // 3145728
  char* sw3T  = sw1T  + 3145728;
  char* sw2T  = sw3T  + 3145728;
  char* Hb    = sw2T  + 3145728;         // 104857600
  char* probs = Hb    + 104857600;       // 65536
  char* idxo  = probs + 65536;           // 65536
  char* lst   = idxo  + 65536;           // 69632
  char* psl   = lst   + 69632;           // 69632
  char* cntb  = psl   + 69632;           // 64
  char* offb  = cntb  + 64;              // 64

  (void)hipMemsetAsync(out, 0, (size_t)out_size * 4, stream);

  cvt_x_kernel<<<2048, 256, 0, stream>>>((const float4*)x, (ushort4*)xb, N_TOK * DM / 4);
  transpose_cvt_kernel<<<dim3(32, 12, 8), 256, 0, stream>>>(w1, (unsigned short*)w1T, DM, DFF);
  transpose_cvt_kernel<<<dim3(32, 12, 8), 256, 0, stream>>>(w3, (unsigned short*)w3T, DM, DFF);
  transpose_cvt_kernel<<<dim3(12, 32, 8), 256, 0, stream>>>(w2, (unsigned short*)w2T, DFF, DM);
  transpose_cvt_kernel<<<dim3(32, 12, 1), 256, 0, stream>>>(sw1, (unsigned short*)sw1T, DM, DFF);
  transpose_cvt_kernel<<<dim3(32, 12, 1), 256, 0, stream>>>(sw3, (unsigned short*)sw3T, DM, DFF);
  transpose_cvt_kernel<<<dim3(12, 32, 1), 256, 0, stream>>>(sw2, (unsigned short*)sw2T, DFF, DM);

  gate_kernel<<<512, 256, 0, stream>>>(x, gw, (float*)probs, (int*)idxo);
  route_kernel<<<1, 256, 0, stream>>>((const int*)idxo, (const float*)probs,
                                      (int*)cntb, (int*)offb, (int*)lst, (float*)psl);

  gemm1_kernel<<<dim3(16, 288), 512, 0, stream>>>(xb, w1T, w3T, sw1T, sw3T,
      (const int*)lst, (const int*)cntb, (const int*)offb, (unsigned short*)Hb);

  gemm2_kernel<<<dim3(6, 288), 512, 0, stream>>>(Hb, w2T, sw2T, (const int*)lst, (const int*)cntb,
      (const int*)offb, (const float*)psl, out);
}

// Round 4
// 433.586 us; speedup vs baseline: 1.0573x; 1.0573x over previous
//
#include <hip/hip_runtime.h>
#include <hip/hip_bf16.h>

#define N_TOK 8192
#define DM 768
#define DFF 2048
#define NE 8
#define SHARED_BASE 17408   // routed padded slots max 16384 + 8*127 -> 17408
#define TOTAL_ROWS 25600

typedef __attribute__((ext_vector_type(8))) __bf16 bf16x8;
typedef __attribute__((ext_vector_type(4))) float f32x4;

__device__ __forceinline__ unsigned short f2bf(float f) {
  union { float f; unsigned u; } a; a.f = f;
  unsigned r = a.u + 0x7FFFu + ((a.u >> 16) & 1u);
  return (unsigned short)(r >> 16);
}

__device__ __forceinline__ void gload16(const void* g, void* l) {
  __builtin_amdgcn_global_load_lds((const __attribute__((address_space(1))) void*)g,
                                   (__attribute__((address_space(3))) void*)l, 16, 0, 0);
}

// ---------------- prep kernels ----------------

__global__ void cvt_x_kernel(const float4* __restrict__ src, ushort4* __restrict__ dst, int n4) {
  int stride = gridDim.x * blockDim.x;
  for (int i = blockIdx.x * blockDim.x + threadIdx.x; i < n4; i += stride) {
    float4 v = src[i];
    ushort4 o;
    o.x = f2bf(v.x); o.y = f2bf(v.y); o.z = f2bf(v.z); o.w = f2bf(v.w);
    dst[i] = o;
  }
}

__global__ void transpose_cvt_kernel(const float* __restrict__ src, unsigned short* __restrict__ dst,
                                     int R, int C) {
  __shared__ float tile[64][65];
  const float* s = src + (size_t)blockIdx.z * R * C;
  unsigned short* d = dst + (size_t)blockIdx.z * R * C;
  int c0 = blockIdx.x * 64, r0 = blockIdx.y * 64;
  int tx = threadIdx.x & 63, ty = threadIdx.x >> 6;
#pragma unroll
  for (int i = 0; i < 16; i++) {
    int row = i * 4 + ty;
    tile[row][tx] = s[(size_t)(r0 + row) * C + c0 + tx];
  }
  __syncthreads();
#pragma unroll
  for (int i = 0; i < 16; i++) {
    int row = i * 4 + ty;
    d[(size_t)(c0 + row) * R + r0 + tx] = f2bf(tile[tx][row]);
  }
}

// gate: 4 waves x 4 tokens each, gw transposed in LDS, fp64 accumulation, no atomics.
__global__ __launch_bounds__(256) void gate_kernel(
    const float* __restrict__ x, const float* __restrict__ gw,
    float* __restrict__ probs, int* __restrict__ idxo) {
  __shared__ float gws[8][768];
  const int tid = threadIdx.x;
  for (int i = tid; i < DM * 2; i += 256) {
    float4 v = ((const float4*)gw)[i];
    int dd = i >> 1;
    int e0 = (i & 1) * 4;
    gws[e0 + 0][dd] = v.x; gws[e0 + 1][dd] = v.y;
    gws[e0 + 2][dd] = v.z; gws[e0 + 3][dd] = v.w;
  }
  __syncthreads();
  const int lane = tid & 63, wv = tid >> 6;
  const int tok0 = blockIdx.x * 16 + wv * 4;
  for (int i = 0; i < 4; i++) {
    const int n = tok0 + i;
    const float* xr = x + (size_t)n * DM;
    float xv[12];
#pragma unroll
    for (int it = 0; it < 12; it++) xv[it] = xr[it * 64 + lane];
    double acc[8];
#pragma unroll
    for (int e = 0; e < 8; e++) {
      double a = 0.0;
#pragma unroll
      for (int it = 0; it < 12; it++) a += (double)xv[it] * (double)gws[e][it * 64 + lane];
      acc[e] = a;
    }
#pragma unroll
    for (int off = 32; off > 0; off >>= 1)
#pragma unroll
      for (int e = 0; e < 8; e++) acc[e] += __shfl_xor(acc[e], off);
    if (lane == 0) {
      int e0 = 0; double v0 = acc[0];
#pragma unroll
      for (int e = 1; e < 8; e++) if (acc[e] > v0) { v0 = acc[e]; e0 = e; }
      int e1 = -1; double v1 = -1e300;
#pragma unroll
      for (int e = 0; e < 8; e++) if (e != e0 && acc[e] > v1) { v1 = acc[e]; e1 = e; }
      double p0 = 1.0 / (1.0 + exp(v1 - v0));
      probs[n * 2 + 0] = (float)p0;
      probs[n * 2 + 1] = (float)(1.0 - p0);
      idxo[n * 2 + 0] = e0;
      idxo[n * 2 + 1] = e1;
    }
  }
}

// route: single block, deterministic prefix-scan scatter (128-aligned segments).
// Writes cnt/offs/list and slot_of (token,k) -> slot for the combine pass.
__global__ __launch_bounds__(256) void route_kernel(
    const int* __restrict__ idxo,
    int* __restrict__ cnt, int* __restrict__ offs,
    int* __restrict__ list, int* __restrict__ slt) {
  __shared__ int lcnt[256][8];
  __shared__ int lstart[256][8];
  __shared__ int base[8];
  const int t = threadIdx.x;
#pragma unroll
  for (int e = 0; e < 8; e++) lcnt[t][e] = 0;
  __syncthreads();
  const int i0 = t * 64;
  for (int j = 0; j < 64; j++) {
    int e = idxo[i0 + j];
    lcnt[t][e]++;
  }
  __syncthreads();
  if (t < 8) {
    int run = 0;
    for (int tt = 0; tt < 256; tt++) { lstart[tt][t] = run; run += lcnt[tt][t]; }
    base[t] = run;
  }
  __syncthreads();
  if (t == 0) {
    int cum = 0;
    for (int e = 0; e < 8; e++) {
      int tot = base[e];
      cnt[e] = tot; offs[e] = cum;
      base[e] = cum;
      cum += (tot + 127) & ~127;
    }
    offs[8] = cum;
  }
  __syncthreads();
#pragma unroll
  for (int e = 0; e < 8; e++) lcnt[t][e] = base[e] + lstart[t][e];
  for (int j = 0; j < 64; j++) {
    int i = i0 + j;
    int e = idxo[i];
    int pos = lcnt[t][e]++;
    list[pos] = i >> 1;
    slt[i] = pos;
  }
}

// ---------------- GEMM1: H = silu(x@w1) * (x@w3), bf16 out ----------------
// block tile 128(M) x 64(F), BK=64, 256 threads (4 waves, 2x2), wave tile 64x32.
__global__ __launch_bounds__(256, 2) void gemm1_kernel(
    const char* __restrict__ xb,     // bf16 [8192][768]
    const char* __restrict__ w1T,    // bf16 [8][2048][768]
    const char* __restrict__ w3T,
    const char* __restrict__ sw1T,   // bf16 [2048][768]
    const char* __restrict__ sw3T,
    const int* __restrict__ list, const int* __restrict__ cnt, const int* __restrict__ offs,
    unsigned short* __restrict__ Hb) // bf16 [25600][2048]
{
  __shared__ unsigned short Al[128 * 64];
  __shared__ unsigned short B1l[64 * 64];
  __shared__ unsigned short B3l[64 * 64];

  const int by = blockIdx.y;
  const int f0 = blockIdx.x * 64;
  const int tid = threadIdx.x;
  const int lane = tid & 63;
  const int wv = tid >> 6;
  const int wm = wv >> 1, wn = wv & 1;
  const int wflat = tid & ~63;

  const char *w1p, *w3p;
  int base_slot, tbase, cnt_e, offs_e = 0;
  const bool is_shared = (by >= 512);
  if (!is_shared) {
    int e = by >> 6, t = by & 63;
    cnt_e = cnt[e];
    if (t * 128 >= cnt_e) return;
    offs_e = offs[e];
    base_slot = offs_e + t * 128;
    tbase = t * 128;
    w1p = w1T + (size_t)e * DFF * DM * 2;
    w3p = w3T + (size_t)e * DFF * DM * 2;
  } else {
    int t = by - 512;
    base_slot = SHARED_BASE + t * 128;
    tbase = t * 128;
    cnt_e = 1 << 30;
    w1p = sw1T; w3p = sw3T;
  }

  const int brow = tid >> 3;  // 0..31
  const int bcol = tid & 7;

  size_t abase[4];
#pragma unroll
  for (int it = 0; it < 4; it++) {
    int row = it * 32 + brow;   // 0..127
    int tok;
    if (is_shared) tok = tbase + row;
    else {
      int ie = tbase + row;
      if (ie >= cnt_e) ie = cnt_e - 1;
      tok = list[offs_e + ie];
    }
    abase[it] = (size_t)tok * (DM * 2) + (size_t)((bcol ^ (row & 7)) << 4);
  }
  size_t bbase[2];
#pragma unroll
  for (int it = 0; it < 2; it++) {
    int row = it * 32 + brow;   // 0..63
    bbase[it] = (size_t)(f0 + row) * (DM * 2) + (size_t)((bcol ^ (row & 7)) << 4);
  }

  f32x4 acc1[4][2], acc3[4][2];
  const f32x4 z4 = {0.f, 0.f, 0.f, 0.f};
#pragma unroll
  for (int mi = 0; mi < 4; mi++)
#pragma unroll
    for (int ni = 0; ni < 2; ni++) { acc1[mi][ni] = z4; acc3[mi][ni] = z4; }

  const int ml = lane & 15, kg = lane >> 4;

  for (int ks = 0; ks < 12; ks++) {
#pragma unroll
    for (int it = 0; it < 4; it++)
      gload16(xb + abase[it] + ks * 128, (char*)Al + (size_t)((it * 256 + wflat) * 16));
#pragma unroll
    for (int it = 0; it < 2; it++) {
      gload16(w1p + bbase[it] + ks * 128, (char*)B1l + (size_t)((it * 256 + wflat) * 16));
      gload16(w3p + bbase[it] + ks * 128, (char*)B3l + (size_t)((it * 256 + wflat) * 16));
    }
    __syncthreads();
#pragma unroll
    for (int kk = 0; kk < 2; kk++) {
      const int kblk = kk * 4 + kg;
      bf16x8 af[4], b1f[2], b3f[2];
#pragma unroll
      for (int mi = 0; mi < 4; mi++) {
        int m = wm * 64 + mi * 16 + ml;
        af[mi] = *(const bf16x8*)((const char*)Al + m * 128 + ((kblk ^ (ml & 7)) << 4));
      }
#pragma unroll
      for (int ni = 0; ni < 2; ni++) {
        int nn = wn * 32 + ni * 16 + ml;
        int boff = nn * 128 + ((kblk ^ (ml & 7)) << 4);
        b1f[ni] = *(const bf16x8*)((const char*)B1l + boff);
        b3f[ni] = *(const bf16x8*)((const char*)B3l + boff);
      }
#pragma unroll
      for (int mi = 0; mi < 4; mi++)
#pragma unroll
        for (int ni = 0; ni < 2; ni++) {
          acc1[mi][ni] = __builtin_amdgcn_mfma_f32_16x16x32_bf16(af[mi], b1f[ni], acc1[mi][ni], 0, 0, 0);
          acc3[mi][ni] = __builtin_amdgcn_mfma_f32_16x16x32_bf16(af[mi], b3f[ni], acc3[mi][ni], 0, 0, 0);
        }
    }
    __syncthreads();
  }

#pragma unroll
  for (int mi = 0; mi < 4; mi++) {
#pragma unroll
    for (int ni = 0; ni < 2; ni++) {
#pragma unroll
      for (int r = 0; r < 4; r++) {
        int row = wm * 64 + mi * 16 + (lane >> 4) * 4 + r;
        int col = f0 + wn * 32 + ni * 16 + ml;
        float h1 = acc1[mi][ni][r], h3 = acc3[mi][ni][r];
        float s = h1 / (1.0f + expf(-h1));
        Hb[(size_t)(base_slot + row) * DFF + col] = f2bf(s * h3);
      }
    }
  }
}

// ---------------- GEMM2: routed -> Ob (plain fp32 stores), shared -> out ----------------
// block tile 128(M) x 128(D), BK=64 (32 steps), 256 threads (4 waves 2x2), wave 64x64.
__global__ __launch_bounds__(256, 2) void gemm2_kernel(
    const char* __restrict__ Hb,     // bf16 [25600][2048]
    const char* __restrict__ w2T,    // bf16 [8][768][2048]
    const char* __restrict__ sw2T,   // bf16 [768][2048]
    const int* __restrict__ cnt, const int* __restrict__ offs,
    float* __restrict__ Ob,          // fp32 [17408][768] per-slot routed output
    float* __restrict__ out)         // fp32 [8192][768] (shared pass, plain stores)
{
  __shared__ unsigned short Al[128 * 64];
  __shared__ unsigned short Bl[128 * 64];

  const int by = blockIdx.y;
  const int d0 = blockIdx.x * 128;
  const int tid = threadIdx.x;
  const int lane = tid & 63;
  const int wv = tid >> 6;
  const int wm = wv >> 1, wn = wv & 1;
  const int wflat = tid & ~63;

  const char* w2p;
  int base_slot, tbase, cnt_e;
  const bool is_shared = (by >= 512);
  if (!is_shared) {
    int e = by >> 6, t = by & 63;
    cnt_e = cnt[e];
    if (t * 128 >= cnt_e) return;
    base_slot = offs[e] + t * 128;
    tbase = t * 128;
    w2p = w2T + (size_t)e * DM * DFF * 2;
  } else {
    int t = by - 512;
    base_slot = SHARED_BASE + t * 128;
    tbase = t * 128;
    cnt_e = 1 << 30;
    w2p = sw2T;
  }

  const int brow = tid >> 3, bcol = tid & 7;
  size_t abase[4], bbase[4];
#pragma unroll
  for (int it = 0; it < 4; it++) {
    int row = it * 32 + brow;  // 0..127
    abase[it] = (size_t)(base_slot + row) * (DFF * 2) + (size_t)((bcol ^ (row & 7)) << 4);
    bbase[it] = (size_t)(d0 + row) * (DFF * 2) + (size_t)((bcol ^ (row & 7)) << 4);
  }

  f32x4 acc[4][4];
  const f32x4 z4 = {0.f, 0.f, 0.f, 0.f};
#pragma unroll
  for (int mi = 0; mi < 4; mi++)
#pragma unroll
    for (int ni = 0; ni < 4; ni++) acc[mi][ni] = z4;

  const int ml = lane & 15, kg = lane >> 4;

  for (int ks = 0; ks < 32; ks++) {
#pragma unroll
    for (int it = 0; it < 4; it++) {
      gload16(Hb + abase[it] + ks * 128, (char*)Al + (size_t)((it * 256 + wflat) * 16));
      gload16(w2p + bbase[it] + ks * 128, (char*)Bl + (size_t)((it * 256 + wflat) * 16));
    }
    __syncthreads();
#pragma unroll
    for (int kk = 0; kk < 2; kk++) {
      const int kblk = kk * 4 + kg;
      bf16x8 af[4], bfr[4];
#pragma unroll
      for (int mi = 0; mi < 4; mi++) {
        int m = wm * 64 + mi * 16 + ml;
        af[mi] = *(const bf16x8*)((const char*)Al + m * 128 + ((kblk ^ (ml & 7)) << 4));
      }
#pragma unroll
      for (int ni = 0; ni < 4; ni++) {
        int nn = wn * 64 + ni * 16 + ml;
        bfr[ni] = *(const bf16x8*)((const char*)Bl + nn * 128 + ((kblk ^ (ml & 7)) << 4));
      }
#pragma unroll
      for (int mi = 0; mi < 4; mi++)
#pragma unroll
        for (int ni = 0; ni < 4; ni++)
          acc[mi][ni] = __builtin_amdgcn_mfma_f32_16x16x32_bf16(af[mi], bfr[ni], acc[mi][ni], 0, 0, 0);
    }
    __syncthreads();
  }

#pragma unroll
  for (int mi = 0; mi < 4; mi++) {
#pragma unroll
    for (int r = 0; r < 4; r++) {
      int row = wm * 64 + mi * 16 + (lane >> 4) * 4 + r;
      float* orow = is_shared ? (out + (size_t)(tbase + row) * DM + d0)
                              : (Ob + (size_t)(base_slot + row) * DM + d0);
#pragma unroll
      for (int ni = 0; ni < 4; ni++)
        orow[wn * 64 + ni * 16 + ml] = acc[mi][ni][r];
    }
  }
}

// combine: out[n] += p0*Ob[s0] + p1*Ob[s1], fp32. 192 threads = one float4 per col-chunk.
__global__ __launch_bounds__(192) void combine_kernel(
    const float4* __restrict__ Ob4, const int* __restrict__ slt,
    const float* __restrict__ probs, float4* __restrict__ out4) {
  const int n = blockIdx.x;
  const int t = threadIdx.x;
  const int s0 = slt[2 * n], s1 = slt[2 * n + 1];
  const float p0 = probs[2 * n], p1 = probs[2 * n + 1];
  float4 a = out4[(size_t)n * 192 + t];
  float4 b = Ob4[(size_t)s0 * 192 + t];
  float4 c = Ob4[(size_t)s1 * 192 + t];
  a.x += p0 * b.x + p1 * c.x;
  a.y += p0 * b.y + p1 * c.y;
  a.z += p0 * b.z + p1 * c.z;
  a.w += p0 * b.w + p1 * c.w;
  out4[(size_t)n * 192 + t] = a;
}

// ---------------- launch ----------------

extern "C" void kernel_launch(void* const* d_in, const int* in_sizes, int n_in,
                              void* d_out, int out_size, void* d_ws, size_t ws_size,
                              hipStream_t stream) {
  const float* x   = (const float*)d_in[0];
  const float* gw  = (const float*)d_in[1];
  const float* w1  = (const float*)d_in[2];
  const float* w3  = (const float*)d_in[3];
  const float* w2  = (const float*)d_in[4];
  const float* sw1 = (const float*)d_in[5];
  const float* sw3 = (const float*)d_in[6];
  const float* sw2 = (const float*)d_in[7];
  float* out = (float*)d_out;
  char* ws = (char*)d_ws;

  // ws layout. U is a union: {w1T,w3T,sw1T,sw3T} live during gemm1 only;
  // Ob (fp32 [17408][768] = 53,477,376 B) is written by gemm2 over the same region.
  char* xb   = ws;                       // 12,582,912
  char* w2T  = xb + 12582912;            // 25,165,824
  char* sw2T = w2T + 25165824;           //  3,145,728
  char* U    = sw2T + 3145728;           // 56,623,104 (union region)
  char* w1T  = U;                        // 25,165,824
  char* w3T  = w1T + 25165824;           // 25,165,824
  char* sw1T = w3T + 25165824;           //  3,145,728
  char* sw3T = sw1T + 3145728;           //  3,145,728
  char* Ob   = U;                        // 53,477,376 (aliases w1T.. after gemm1)
  char* Hb   = U + 56623104;             // 104,857,600
  char* probs= Hb + 104857600;           // 65,536
  char* idxo = probs + 65536;            // 65,536
  char* lst  = idxo + 65536;             // 69,632
  char* slt  = lst + 69632;              // 69,632
  char* cntb = slt + 69632;              // 64
  char* offb = cntb + 64;                // 64

  cvt_x_kernel<<<2048, 256, 0, stream>>>((const float4*)x, (ushort4*)xb, N_TOK * DM / 4);
  transpose_cvt_kernel<<<dim3(32, 12, 8), 256, 0, stream>>>(w1, (unsigned short*)w1T, DM, DFF);
  transpose_cvt_kernel<<<dim3(32, 12, 8), 256, 0, stream>>>(w3, (unsigned short*)w3T, DM, DFF);
  transpose_cvt_kernel<<<dim3(12, 32, 8), 256, 0, stream>>>(w2, (unsigned short*)w2T, DFF, DM);
  transpose_cvt_kernel<<<dim3(32, 12, 1), 256, 0, stream>>>(sw1, (unsigned short*)sw1T, DM, DFF);
  transpose_cvt_kernel<<<dim3(32, 12, 1), 256, 0, stream>>>(sw3, (unsigned short*)sw3T, DM, DFF);
  transpose_cvt_kernel<<<dim3(12, 32, 1), 256, 0, stream>>>(sw2, (unsigned short*)sw2T, DFF, DM);

  gate_kernel<<<512, 256, 0, stream>>>(x, gw, (float*)probs, (int*)idxo);
  route_kernel<<<1, 256, 0, stream>>>((const int*)idxo,
                                      (int*)cntb, (int*)offb, (int*)lst, (int*)slt);

  gemm1_kernel<<<dim3(32, 576), 256, 0, stream>>>(xb, w1T, w3T, sw1T, sw3T,
      (const int*)lst, (const int*)cntb, (const int*)offb, (unsigned short*)Hb);

  gemm2_kernel<<<dim3(6, 576), 256, 0, stream>>>(Hb, w2T, sw2T,
      (const int*)cntb, (const int*)offb, (float*)Ob, out);

  combine_kernel<<<N_TOK, 192, 0, stream>>>((const float4*)Ob, (const int*)slt,
                                            (const float*)probs, (float4*)out);
}